// Round 13
// baseline (140.700 us; speedup 1.0000x reference)
//
#include <hip/hip_runtime.h>
#include <math.h>

#define SAI 9
#define NB  4
#define CK  64
#define CV  64
#define HW  1024
#define QT  32     // queries per block
#define RSW2 264   // main sW row stride in shorts (528 B, 16B-aligned)
#define RSTR 68    // fallback kernel LDS stride (words)

typedef __attribute__((ext_vector_type(8))) short bf16x8;
typedef __attribute__((ext_vector_type(4))) float f32x4;
typedef unsigned short u16;
typedef unsigned int u32;

__device__ __forceinline__ u16 f2bf(float x) {           // RNE fp32->bf16
    unsigned u = __float_as_uint(x);
    return (u16)((u + 0x7fff + ((u >> 16) & 1)) >> 16);
}
__device__ __forceinline__ float bf2f(u16 s) {
    return __uint_as_float(((unsigned)s) << 16);
}
__device__ __forceinline__ unsigned pk2(float a, float b) {   // RNE pair pack
    return (unsigned)f2bf(a) | ((unsigned)f2bf(b) << 16);
}
// Barrier that waits only LDS (lgkmcnt), leaving global loads in flight.
__device__ __forceinline__ void lds_barrier() {
    __asm__ __volatile__("s_waitcnt lgkmcnt(0)\n\ts_barrier" ::: "memory");
}

// ---------------- prep: fp32 -> bf16 fragments in MFMA order ----------------
// K granule gg = g16*2+ks: elem(lane,j) = K[c=ks*32+quad*8+j][p=g16*16+l15] (hi only)
// V granule gg = kb*4+cg:  elem(lane,j) = V[p=kb*32+quad*8+j][c=cg*16+l15]
__global__ __launch_bounds__(256) void cfa_prep(
    const float* __restrict__ keys, const float* __restrict__ vals,
    u16* __restrict__ khi, u16* __restrict__ vbf)
{
    const int gid = blockIdx.x * 256 + threadIdx.x;
    const int isV = gid >= (SAI * NB * 8192);
    const int id  = isV ? gid - SAI * NB * 8192 : gid;
    const int f   = id >> 13;            // frame = s*NB+b
    const int r   = id & 8191;
    const int lane = r & 63;
    const int gg   = r >> 6;             // 0..127
    const int l15 = lane & 15, quad = lane >> 4;
    const size_t fb = (size_t)f * (64 * 1024);

    if (!isV) {
        const int p  = (gg >> 1) * 16 + l15;
        const int c0 = (gg & 1) * 32 + quad * 8;
        const float* src = keys + fb + (size_t)c0 * HW + p;
        float x[8];
#pragma unroll
        for (int j = 0; j < 8; ++j) x[j] = src[(size_t)j * HW];
        uint4 ph;
        u32* php = (u32*)&ph;
#pragma unroll
        for (int h2 = 0; h2 < 4; ++h2)
            php[h2] = pk2(x[h2 * 2], x[h2 * 2 + 1]);
        *(uint4*)&khi[fb + (size_t)gg * 512 + lane * 8] = ph;
    } else {
        const int p = (gg >> 2) * 32 + quad * 8;
        const int c = (gg & 3) * 16 + l15;
        const float* src = vals + fb + (size_t)c * HW + p;
        const float4 a = *(const float4*)src;
        const float4 b = *(const float4*)(src + 4);
        uint4 pv;
        pv.x = pk2(a.x, a.y); pv.y = pk2(a.z, a.w);
        pv.z = pk2(b.x, b.y); pv.w = pk2(b.z, b.w);
        *(uint4*)&vbf[fb + (size_t)gg * 512 + lane * 8] = pv;
    }
}

// ---------------- main: 512 threads, 256-key tiles, 4 barrier groups -------
// Grid = 1152 linear blocks; f = i % 36, qt = i / 36 (XCD frame clustering).
// 8 waves; wave w owns keys [t*256+w*32,+32) in phase1 (A=K, B=Qhi/Qlo,
// 2-term product). exp -> sW[t&1][q][256k]. phase2: wave w owns channel
// group (w&3), query half (w>>2), all 256 keys -> single f32x4 acc.
// K(t+1) prefetched before the lgkm-only barrier (loads stay in flight).
__global__ __launch_bounds__(512, 4) void cfa_main(
    const u16* __restrict__ khi, const u16* __restrict__ vbf,
    const float* __restrict__ query, const float* __restrict__ disp,
    const int* __restrict__ seq,
    float* __restrict__ numW, float* __restrict__ denW)
{
    __shared__ alignas(16) u16 sW[2][QT * RSW2];   // 2 x 16896 B
    __shared__ float sDen[8 * QT];

    const int tid = threadIdx.x;
    const int w = tid >> 6;             // 0..7
    const int lane = tid & 63;
    const int l15 = lane & 15, quad = lane >> 4;
    const int f  = blockIdx.x % 36;     // frame = s*NB+b
    const int qt = blockIdx.x / 36;     // query tile
    const int s  = f / NB;
    const int b  = f % NB;
    const int p0 = qt * QT;
    const size_t fb = (size_t)f * (64 * 1024);
    const int cg  = w & 3;              // phase-2 channel group
    const int qh2 = w >> 2;             // phase-2 query half

    const float d0 = (float)seq[(b * SAI + s) * 2 + 0] - 5.f;
    const float d1 = (float)seq[(b * SAI + s) * 2 + 1] - 5.f;
    const float dist = sqrtf(d0 * d0 + d1 * d1);

    // Q B-frags (n=q -> l15, k=channel -> quad*8+j), hi/lo
    bf16x8 qh[2][2], ql[2][2];
#pragma unroll
    for (int q2 = 0; q2 < 2; ++q2)
#pragma unroll
        for (int ks = 0; ks < 2; ++ks)
#pragma unroll
            for (int j = 0; j < 8; ++j) {
                float x = query[(size_t)(b * CK + ks * 32 + quad * 8 + j) * HW + p0 + q2 * 16 + l15];
                u16 h = f2bf(x);
                qh[q2][ks][j] = (short)h;
                ql[q2][ks][j] = (short)f2bf(x - bf2f(h));
            }

    f32x4 acc;                          // q = qh2*16+quad*4+r, c = cg*16+l15
#pragma unroll
    for (int r = 0; r < 4; ++r) acc[r] = 0.f;
    float den[2] = {0.f, 0.f};

    uint4 kbh[2][2];    // K register buffer [kt][ks]
#define LOADK(tt)                                                              \
    {                                                                          \
        _Pragma("unroll") for (int kt = 0; kt < 2; ++kt)                       \
        _Pragma("unroll") for (int ks = 0; ks < 2; ++ks) {                     \
            const size_t ka = fb +                                             \
                (size_t)((((tt) * 16 + w * 2 + kt) * 2) + ks) * 512 + lane * 8;\
            kbh[kt][ks] = *(const uint4*)&khi[ka];                             \
        }                                                                      \
    }

    LOADK(0);   // prologue: K(0) in flight

    for (int t = 0; t < 4; ++t) {
        u16* const wbuf = sW[t & 1];

        // ---- issue V(t): 8 key-blocks of 32 for channel group cg
        uint4 vb[8];
#pragma unroll
        for (int k2 = 0; k2 < 8; ++k2)
            vb[k2] = *(const uint4*)&vbf[fb + (size_t)((t * 8 + k2) * 4 + cg) * 512 + lane * 8];
        const float4 dv0 = *(const float4*)(disp + b * HW + t * 256 + w * 32 + quad * 4);
        const float4 dv1 = *(const float4*)(disp + b * HW + t * 256 + w * 32 + 16 + quad * 4);

        // ---- phase 1: S for this wave's 32 keys (K already in regs)
        f32x4 sc[2][2];
#pragma unroll
        for (int q2 = 0; q2 < 2; ++q2)
#pragma unroll
            for (int kt = 0; kt < 2; ++kt)
#pragma unroll
                for (int r = 0; r < 4; ++r) sc[q2][kt][r] = 0.f;

#pragma unroll
        for (int kt = 0; kt < 2; ++kt)
#pragma unroll
            for (int ks = 0; ks < 2; ++ks) {
                const bf16x8 kh = __builtin_bit_cast(bf16x8, kbh[kt][ks]);
#pragma unroll
                for (int q2 = 0; q2 < 2; ++q2) {
                    sc[q2][kt] = __builtin_amdgcn_mfma_f32_16x16x32_bf16(kh, qh[q2][ks], sc[q2][kt], 0, 0, 0);
                    sc[q2][kt] = __builtin_amdgcn_mfma_f32_16x16x32_bf16(kh, ql[q2][ks], sc[q2][kt], 0, 0, 0);
                }
            }

        // ---- mask + exp -> sW[t&1] (b64 packed stores), den partials
#pragma unroll
        for (int kt = 0; kt < 2; ++kt) {
            const float4 dv = kt ? dv1 : dv0;
            const float m0 = (fabsf(dist * dv.x) > 0.5f) ? 1.f : 0.f;
            const float m1 = (fabsf(dist * dv.y) > 0.5f) ? 1.f : 0.f;
            const float m2 = (fabsf(dist * dv.z) > 0.5f) ? 1.f : 0.f;
            const float m3 = (fabsf(dist * dv.w) > 0.5f) ? 1.f : 0.f;
#pragma unroll
            for (int q2 = 0; q2 < 2; ++q2) {
                const float e0 = m0 * __expf(sc[q2][kt][0]);
                const float e1 = m1 * __expf(sc[q2][kt][1]);
                const float e2 = m2 * __expf(sc[q2][kt][2]);
                const float e3 = m3 * __expf(sc[q2][kt][3]);
                den[q2] += (e0 + e1) + (e2 + e3);
                uint2 pk;
                pk.x = pk2(e0, e1);
                pk.y = pk2(e2, e3);
                *(uint2*)&wbuf[(q2 * 16 + l15) * RSW2 + w * 32 + kt * 16 + quad * 4] = pk;
            }
        }

        // ---- prefetch K(t+1): in flight across barrier + phase2
        LOADK((t + 1) & 3);

        lds_barrier();   // waits lgkmcnt only; vmcnt (K/V loads) NOT drained

        // ---- phase 2: acc += W.V (wave w: q-half qh2, channels cg*16..+15)
#pragma unroll
        for (int k2 = 0; k2 < 8; ++k2) {
            const bf16x8 vf = __builtin_bit_cast(bf16x8, vb[k2]);
            const bf16x8 wf = __builtin_bit_cast(bf16x8,
                *(const uint4*)&wbuf[(qh2 * 16 + l15) * RSW2 + k2 * 32 + quad * 8]);
            acc = __builtin_amdgcn_mfma_f32_16x16x32_bf16(wf, vf, acc, 0, 0, 0);
        }
    }
#undef LOADK

    // ---- den: sum over quads (shfl 16/32), stage per-wave, sum over 8 waves
#pragma unroll
    for (int q2 = 0; q2 < 2; ++q2) {
        den[q2] += __shfl_xor(den[q2], 16, 64);
        den[q2] += __shfl_xor(den[q2], 32, 64);
    }
    if (quad == 0) {
#pragma unroll
        for (int q2 = 0; q2 < 2; ++q2)
            sDen[w * QT + q2 * 16 + l15] = den[q2];
    }
    __syncthreads();
    if (tid < QT) {
        float dsum = 0.f;
#pragma unroll
        for (int ww = 0; ww < 8; ++ww) dsum += sDen[ww * QT + tid];
        denW[(size_t)f * HW + p0 + tid] = dsum;
    }

    // ---- numW (c = l15 fastest: coalesced 64B segments)
#pragma unroll
    for (int r = 0; r < 4; ++r) {
        const int q = qh2 * 16 + quad * 4 + r;
        const int c = cg * 16 + l15;
        numW[((size_t)f * HW + p0 + q) * CV + c] = acc[r];
    }
}

// ---------------- reduce: sum 9 frame partials, divide ----------------
__global__ __launch_bounds__(256) void cfa_reduce(
    const float* __restrict__ numW, const float* __restrict__ denW,
    float* __restrict__ out)
{
    const int tid = threadIdx.x;
    const int bid = blockIdx.x;            // 0..1023
    const int b = bid >> 8;
    const int p = (bid & 255) * 4 + (tid >> 6);
    const int c = tid & 63;
    float num = 0.f, den = 0.f;
#pragma unroll
    for (int s = 0; s < SAI; ++s) {
        num += numW[(((size_t)(s * NB + b)) * HW + p) * CV + c];
        den += denW[((size_t)(s * NB + b)) * HW + p];
    }
    out[((size_t)b * CV + c) * HW + p] = num / den;
}

// ---------------- fallback (R4-style, proven): used if ws too small ----------
__global__ __launch_bounds__(256, 2) void cfa_fb(
    const float* __restrict__ keys, const float* __restrict__ vals,
    const float* __restrict__ query, const float* __restrict__ disp,
    const int* __restrict__ seq,
    float* __restrict__ numW, float* __restrict__ denW,
    float* __restrict__ out, int nS)
{
    __shared__ alignas(16) unsigned int sV[CV * RSTR];
    __shared__ alignas(16) unsigned int sWb[32 * RSTR];
    __shared__ float sDen[4 * 32];
    __shared__ float sDenTot[32];

    const int tid  = threadIdx.x;
    const int w    = tid >> 6;
    const int lane = tid & 63;
    const int l15  = lane & 15;
    const int quad = lane >> 4;
    const int b    = blockIdx.y;
    const int s0   = blockIdx.z;
    const int p0   = blockIdx.x * 32;
    const bool direct = (nS == SAI);

    bf16x8 qhi[2][2], qlo[2][2];
#pragma unroll
    for (int qt = 0; qt < 2; ++qt)
#pragma unroll
        for (int ks = 0; ks < 2; ++ks)
#pragma unroll
            for (int j = 0; j < 8; ++j) {
                float x = query[(size_t)(b * CK + ks * 32 + quad * 8 + j) * HW + p0 + qt * 16 + l15];
                u16 h = f2bf(x);
                qhi[qt][ks][j] = (short)h;
                qlo[qt][ks][j] = (short)f2bf(x - bf2f(h));
            }

    f32x4 acc[2];
#pragma unroll
    for (int qt = 0; qt < 2; ++qt)
#pragma unroll
        for (int r = 0; r < 4; ++r) acc[qt][r] = 0.f;
    float denacc[2][4] = {{0.f,0.f,0.f,0.f},{0.f,0.f,0.f,0.f}};

    for (int si = 0; si < nS; ++si) {
        const int s = s0 + si;
        const float d0 = (float)seq[(b * SAI + s) * 2 + 0] - 5.f;
        const float d1 = (float)seq[(b * SAI + s) * 2 + 1] - 5.f;
        const float dist = sqrtf(d0 * d0 + d1 * d1);
        const float* Kf = keys + (size_t)(s * NB + b) * CK * HW;
        const float* Vf = vals + (size_t)(s * NB + b) * CV * HW;

        for (int t = 0; t < HW / 128; ++t) {
            const int t128 = t * 128;
            __syncthreads();
#pragma unroll
            for (int it = 0; it < 4; ++it) {
                const int gidx = it * 256 + tid;
                const int c = gidx >> 4;
                const int g = gidx & 15;
                const float* vp = Vf + (size_t)c * HW + t128 + g * 8;
                const float4 f0 = *(const float4*)(vp);
                const float4 f1 = *(const float4*)(vp + 4);
                uint4 pk;
                pk.x = pk2(f0.x, f0.y); pk.y = pk2(f0.z, f0.w);
                pk.z = pk2(f1.x, f1.y); pk.w = pk2(f1.z, f1.w);
                *(uint4*)&sV[c * RSTR + g * 4] = pk;
            }

            f32x4 sc[2][2];
#pragma unroll
            for (int qt = 0; qt < 2; ++qt)
#pragma unroll
                for (int kt = 0; kt < 2; ++kt)
#pragma unroll
                    for (int r = 0; r < 4; ++r) sc[qt][kt][r] = 0.f;

            const int keyBase = t128 + w * 32 + l15;
#pragma unroll
            for (int kt = 0; kt < 2; ++kt)
#pragma unroll
                for (int ks = 0; ks < 2; ++ks) {
                    bf16x8 kh, kl;
#pragma unroll
                    for (int j = 0; j < 8; ++j) {
                        float x = Kf[(size_t)(ks * 32 + quad * 8 + j) * HW + keyBase + kt * 16];
                        u16 h = f2bf(x);
                        kh[j] = (short)h;
                        kl[j] = (short)f2bf(x - bf2f(h));
                    }
#pragma unroll
                    for (int qt = 0; qt < 2; ++qt) {
                        sc[qt][kt] = __builtin_amdgcn_mfma_f32_16x16x32_bf16(qhi[qt][ks], kh, sc[qt][kt], 0, 0, 0);
                        sc[qt][kt] = __builtin_amdgcn_mfma_f32_16x16x32_bf16(qhi[qt][ks], kl, sc[qt][kt], 0, 0, 0);
                        sc[qt][kt] = __builtin_amdgcn_mfma_f32_16x16x32_bf16(qlo[qt][ks], kh, sc[qt][kt], 0, 0, 0);
                    }
                }

#pragma unroll
            for (int kt = 0; kt < 2; ++kt) {
                const int kk = w * 32 + kt * 16 + l15;
                const float dvv = disp[b * HW + t128 + kk];
                const float msk = (fabsf(dist * dvv) > 0.5f) ? 1.f : 0.f;
#pragma unroll
                for (int qt = 0; qt < 2; ++qt)
#pragma unroll
                    for (int r = 0; r < 4; ++r) {
                        const float e = msk * __expf(sc[qt][kt][r]);
                        denacc[qt][r] += e;
                        const int q = qt * 16 + quad * 4 + r;
                        ((u16*)sWb)[q * (2 * RSTR) + kk] = f2bf(e);
                    }
            }
            __syncthreads();

            const int c = w * 16 + l15;
#pragma unroll
            for (int ks2 = 0; ks2 < 4; ++ks2) {
                const int g = ks2 * 4 + quad;
                uint4 vr = *(uint4*)&sV[c * RSTR + g * 4];
                bf16x8 vfrag = __builtin_bit_cast(bf16x8, vr);
#pragma unroll
                for (int qt = 0; qt < 2; ++qt) {
                    const int q = qt * 16 + l15;
                    uint4 wr = *(uint4*)&sWb[q * RSTR + g * 4];
                    bf16x8 wfrag = __builtin_bit_cast(bf16x8, wr);
                    acc[qt] = __builtin_amdgcn_mfma_f32_16x16x32_bf16(wfrag, vfrag, acc[qt], 0, 0, 0);
                }
            }
        }
    }

#pragma unroll
    for (int off = 1; off < 16; off <<= 1)
#pragma unroll
        for (int qt = 0; qt < 2; ++qt)
#pragma unroll
            for (int r = 0; r < 4; ++r)
                denacc[qt][r] += __shfl_xor(denacc[qt][r], off, 64);

    if (l15 == 0)
#pragma unroll
        for (int qt = 0; qt < 2; ++qt)
#pragma unroll
            for (int r = 0; r < 4; ++r)
                sDen[w * 32 + qt * 16 + quad * 4 + r] = denacc[qt][r];
    __syncthreads();

    if (tid < 32) {
        const float d = sDen[tid] + sDen[32 + tid] + sDen[64 + tid] + sDen[96 + tid];
        if (direct) sDenTot[tid] = d;
        else        denW[(size_t)(s0 * NB + b) * HW + p0 + tid] = d;
    }

    if (direct) {
        __syncthreads();
#pragma unroll
        for (int qt = 0; qt < 2; ++qt)
#pragma unroll
            for (int r = 0; r < 4; ++r) {
                const int q = qt * 16 + quad * 4 + r;
                const int c = w * 16 + l15;
                out[((size_t)b * CV + c) * HW + p0 + q] = acc[qt][r] / sDenTot[q];
            }
    } else {
#pragma unroll
        for (int qt = 0; qt < 2; ++qt)
#pragma unroll
            for (int r = 0; r < 4; ++r) {
                const int q = qt * 16 + quad * 4 + r;
                const int c = w * 16 + l15;
                numW[((size_t)(s0 * NB + b) * HW + p0 + q) * CV + c] = acc[qt][r];
            }
    }
}

extern "C" void kernel_launch(void* const* d_in, const int* in_sizes, int n_in,
                              void* d_out, int out_size, void* d_ws, size_t ws_size,
                              hipStream_t stream) {
    const float* keys  = (const float*)d_in[0];
    const float* vals  = (const float*)d_in[1];
    const float* query = (const float*)d_in[2];
    const float* disp  = (const float*)d_in[3];
    const int*   seq   = (const int*)d_in[4];
    float* out = (float*)d_out;

    const size_t numElems = (size_t)SAI * NB * HW * CV;     // 2359296
    const size_t denElems = (size_t)SAI * NB * HW;          // 36864
    const size_t partBytes = (numElems + denElems) * sizeof(float);  // 9584640
    const size_t fragBytes = (size_t)SAI * NB * CK * HW * 2;         // 4718592 each
    const size_t needFull = partBytes + 2 * fragBytes;               // ~18 MiB

    float* numW = (float*)d_ws;
    float* denW = numW + numElems;

    if (ws_size >= needFull) {
        u16* khi = (u16*)((char*)d_ws + partBytes);
        u16* vbf = (u16*)((char*)khi + fragBytes);
        hipLaunchKernelGGL(cfa_prep, dim3(2 * SAI * NB * 8192 / 256), dim3(256), 0, stream,
                           keys, vals, khi, vbf);
        hipLaunchKernelGGL(cfa_main, dim3(36 * (HW / QT)), dim3(512), 0, stream,
                           khi, vbf, query, disp, seq, numW, denW);
        hipLaunchKernelGGL(cfa_reduce, dim3(1024), dim3(256), 0, stream,
                           numW, denW, out);
    } else if (ws_size >= partBytes) {
        hipLaunchKernelGGL(cfa_fb, dim3(HW / 32, NB, SAI), dim3(256), 0, stream,
                           keys, vals, query, disp, seq, numW, denW, (float*)nullptr, 1);
        hipLaunchKernelGGL(cfa_reduce, dim3(1024), dim3(256), 0, stream,
                           numW, denW, out);
    } else {
        hipLaunchKernelGGL(cfa_fb, dim3(HW / 32, NB, 1), dim3(256), 0, stream,
                           keys, vals, query, disp, seq,
                           (float*)nullptr, (float*)nullptr, out, SAI);
    }
}

// Round 14
// 132.784 us; speedup vs baseline: 1.0596x; 1.0596x over previous
//
#include <hip/hip_runtime.h>
#include <math.h>

#define SAI 9
#define NB  4
#define CK  64
#define CV  64
#define HW  1024
#define QT  32     // queries per block
#define RSW2 264   // main sW row stride in shorts (528 B, 16B-aligned)
#define RSTR 68    // fallback kernel LDS stride (words)

typedef __attribute__((ext_vector_type(8))) short bf16x8;
typedef __attribute__((ext_vector_type(4))) float f32x4;
typedef unsigned short u16;
typedef unsigned int u32;

__device__ __forceinline__ u16 f2bf(float x) {           // RNE fp32->bf16
    unsigned u = __float_as_uint(x);
    return (u16)((u + 0x7fff + ((u >> 16) & 1)) >> 16);
}
__device__ __forceinline__ float bf2f(u16 s) {
    return __uint_as_float(((unsigned)s) << 16);
}
__device__ __forceinline__ unsigned pk2(float a, float b) {   // RNE pair pack
    return (unsigned)f2bf(a) | ((unsigned)f2bf(b) << 16);
}
// Barrier that waits only LDS (lgkmcnt), leaving global loads in flight.
__device__ __forceinline__ void lds_barrier() {
    __asm__ __volatile__("s_waitcnt lgkmcnt(0)\n\ts_barrier" ::: "memory");
}

// ---------------- prep: fp32 -> bf16 fragments in MFMA order ----------------
// K granule gg = g16*2+ks: elem(lane,j) = K[c=ks*32+quad*8+j][p=g16*16+l15] (hi only)
// V granule gg = kb*4+cg:  elem(lane,j) = V[p=kb*32+quad*8+j][c=cg*16+l15]
__global__ __launch_bounds__(256) void cfa_prep(
    const float* __restrict__ keys, const float* __restrict__ vals,
    u16* __restrict__ khi, u16* __restrict__ vbf)
{
    const int gid = blockIdx.x * 256 + threadIdx.x;
    const int isV = gid >= (SAI * NB * 8192);
    const int id  = isV ? gid - SAI * NB * 8192 : gid;
    const int f   = id >> 13;            // frame = s*NB+b
    const int r   = id & 8191;
    const int lane = r & 63;
    const int gg   = r >> 6;             // 0..127
    const int l15 = lane & 15, quad = lane >> 4;
    const size_t fb = (size_t)f * (64 * 1024);

    if (!isV) {
        const int p  = (gg >> 1) * 16 + l15;
        const int c0 = (gg & 1) * 32 + quad * 8;
        const float* src = keys + fb + (size_t)c0 * HW + p;
        float x[8];
#pragma unroll
        for (int j = 0; j < 8; ++j) x[j] = src[(size_t)j * HW];
        uint4 ph;
        u32* php = (u32*)&ph;
#pragma unroll
        for (int h2 = 0; h2 < 4; ++h2)
            php[h2] = pk2(x[h2 * 2], x[h2 * 2 + 1]);
        *(uint4*)&khi[fb + (size_t)gg * 512 + lane * 8] = ph;
    } else {
        const int p = (gg >> 2) * 32 + quad * 8;
        const int c = (gg & 3) * 16 + l15;
        const float* src = vals + fb + (size_t)c * HW + p;
        const float4 a = *(const float4*)src;
        const float4 b = *(const float4*)(src + 4);
        uint4 pv;
        pv.x = pk2(a.x, a.y); pv.y = pk2(a.z, a.w);
        pv.z = pk2(b.x, b.y); pv.w = pk2(b.z, b.w);
        *(uint4*)&vbf[fb + (size_t)gg * 512 + lane * 8] = pv;
    }
}

// ---------------- main: 512 threads, 256-key tiles, 2 blocks/CU ------------
// Grid = 1152 linear blocks; f = i % 36, qt = i / 36 (XCD frame clustering).
// 8 waves; wave w owns keys [t*256+w*32,+32) in phase1 (A=K, B=Qhi/Qlo,
// 2-term product). exp -> sW[t&1][q][256k]. phase2: wave w owns channel
// group (w&3), query half (w>>2), all 256 keys -> single f32x4 acc.
// K(t+1) prefetched before the lgkm-only barrier (loads stay in flight).
// __launch_bounds__(512,2): 4 waves/SIMD -> 128-VGPR cap (R13's (512,4)
// capped at 64 VGPR and spilled 67 MB to scratch — measured).
__global__ __launch_bounds__(512, 2) void cfa_main(
    const u16* __restrict__ khi, const u16* __restrict__ vbf,
    const float* __restrict__ query, const float* __restrict__ disp,
    const int* __restrict__ seq,
    float* __restrict__ numW, float* __restrict__ denW)
{
    __shared__ alignas(16) u16 sW[2][QT * RSW2];   // 2 x 16896 B
    __shared__ float sDen[8 * QT];

    const int tid = threadIdx.x;
    const int w = tid >> 6;             // 0..7
    const int lane = tid & 63;
    const int l15 = lane & 15, quad = lane >> 4;
    const int f  = blockIdx.x % 36;     // frame = s*NB+b
    const int qt = blockIdx.x / 36;     // query tile
    const int s  = f / NB;
    const int b  = f % NB;
    const int p0 = qt * QT;
    const size_t fb = (size_t)f * (64 * 1024);
    const int cg  = w & 3;              // phase-2 channel group
    const int qh2 = w >> 2;             // phase-2 query half

    const float d0 = (float)seq[(b * SAI + s) * 2 + 0] - 5.f;
    const float d1 = (float)seq[(b * SAI + s) * 2 + 1] - 5.f;
    const float dist = sqrtf(d0 * d0 + d1 * d1);

    // Q B-frags (n=q -> l15, k=channel -> quad*8+j), hi/lo
    bf16x8 qh[2][2], ql[2][2];
#pragma unroll
    for (int q2 = 0; q2 < 2; ++q2)
#pragma unroll
        for (int ks = 0; ks < 2; ++ks)
#pragma unroll
            for (int j = 0; j < 8; ++j) {
                float x = query[(size_t)(b * CK + ks * 32 + quad * 8 + j) * HW + p0 + q2 * 16 + l15];
                u16 h = f2bf(x);
                qh[q2][ks][j] = (short)h;
                ql[q2][ks][j] = (short)f2bf(x - bf2f(h));
            }

    f32x4 acc;                          // q = qh2*16+quad*4+r, c = cg*16+l15
#pragma unroll
    for (int r = 0; r < 4; ++r) acc[r] = 0.f;
    float den[2] = {0.f, 0.f};

    uint4 kbh[2][2];    // K register buffer [kt][ks]
#define LOADK(tt)                                                              \
    {                                                                          \
        _Pragma("unroll") for (int kt = 0; kt < 2; ++kt)                       \
        _Pragma("unroll") for (int ks = 0; ks < 2; ++ks) {                     \
            const size_t ka = fb +                                             \
                (size_t)((((tt) * 16 + w * 2 + kt) * 2) + ks) * 512 + lane * 8;\
            kbh[kt][ks] = *(const uint4*)&khi[ka];                             \
        }                                                                      \
    }

    LOADK(0);   // prologue: K(0) in flight

    for (int t = 0; t < 4; ++t) {
        u16* const wbuf = sW[t & 1];

        // ---- issue V(t): 8 key-blocks of 32 for channel group cg
        uint4 vb[8];
#pragma unroll
        for (int k2 = 0; k2 < 8; ++k2)
            vb[k2] = *(const uint4*)&vbf[fb + (size_t)((t * 8 + k2) * 4 + cg) * 512 + lane * 8];
        const float4 dv0 = *(const float4*)(disp + b * HW + t * 256 + w * 32 + quad * 4);
        const float4 dv1 = *(const float4*)(disp + b * HW + t * 256 + w * 32 + 16 + quad * 4);

        // ---- phase 1: S for this wave's 32 keys (K already in regs)
        f32x4 sc[2][2];
#pragma unroll
        for (int q2 = 0; q2 < 2; ++q2)
#pragma unroll
            for (int kt = 0; kt < 2; ++kt)
#pragma unroll
                for (int r = 0; r < 4; ++r) sc[q2][kt][r] = 0.f;

#pragma unroll
        for (int kt = 0; kt < 2; ++kt)
#pragma unroll
            for (int ks = 0; ks < 2; ++ks) {
                const bf16x8 kh = __builtin_bit_cast(bf16x8, kbh[kt][ks]);
#pragma unroll
                for (int q2 = 0; q2 < 2; ++q2) {
                    sc[q2][kt] = __builtin_amdgcn_mfma_f32_16x16x32_bf16(kh, qh[q2][ks], sc[q2][kt], 0, 0, 0);
                    sc[q2][kt] = __builtin_amdgcn_mfma_f32_16x16x32_bf16(kh, ql[q2][ks], sc[q2][kt], 0, 0, 0);
                }
            }

        // ---- mask + exp -> sW[t&1] (b64 packed stores), den partials
#pragma unroll
        for (int kt = 0; kt < 2; ++kt) {
            const float4 dv = kt ? dv1 : dv0;
            const float m0 = (fabsf(dist * dv.x) > 0.5f) ? 1.f : 0.f;
            const float m1 = (fabsf(dist * dv.y) > 0.5f) ? 1.f : 0.f;
            const float m2 = (fabsf(dist * dv.z) > 0.5f) ? 1.f : 0.f;
            const float m3 = (fabsf(dist * dv.w) > 0.5f) ? 1.f : 0.f;
#pragma unroll
            for (int q2 = 0; q2 < 2; ++q2) {
                const float e0 = m0 * __expf(sc[q2][kt][0]);
                const float e1 = m1 * __expf(sc[q2][kt][1]);
                const float e2 = m2 * __expf(sc[q2][kt][2]);
                const float e3 = m3 * __expf(sc[q2][kt][3]);
                den[q2] += (e0 + e1) + (e2 + e3);
                uint2 pk;
                pk.x = pk2(e0, e1);
                pk.y = pk2(e2, e3);
                *(uint2*)&wbuf[(q2 * 16 + l15) * RSW2 + w * 32 + kt * 16 + quad * 4] = pk;
            }
        }

        // ---- prefetch K(t+1): in flight across barrier + phase2
        LOADK((t + 1) & 3);

        lds_barrier();   // waits lgkmcnt only; vmcnt (K/V loads) NOT drained

        // ---- phase 2: acc += W.V (wave w: q-half qh2, channels cg*16..+15)
#pragma unroll
        for (int k2 = 0; k2 < 8; ++k2) {
            const bf16x8 vf = __builtin_bit_cast(bf16x8, vb[k2]);
            const bf16x8 wf = __builtin_bit_cast(bf16x8,
                *(const uint4*)&wbuf[(qh2 * 16 + l15) * RSW2 + k2 * 32 + quad * 8]);
            acc = __builtin_amdgcn_mfma_f32_16x16x32_bf16(wf, vf, acc, 0, 0, 0);
        }
    }
#undef LOADK

    // ---- den: sum over quads (shfl 16/32), stage per-wave, sum over 8 waves
#pragma unroll
    for (int q2 = 0; q2 < 2; ++q2) {
        den[q2] += __shfl_xor(den[q2], 16, 64);
        den[q2] += __shfl_xor(den[q2], 32, 64);
    }
    if (quad == 0) {
#pragma unroll
        for (int q2 = 0; q2 < 2; ++q2)
            sDen[w * QT + q2 * 16 + l15] = den[q2];
    }
    __syncthreads();
    if (tid < QT) {
        float dsum = 0.f;
#pragma unroll
        for (int ww = 0; ww < 8; ++ww) dsum += sDen[ww * QT + tid];
        denW[(size_t)f * HW + p0 + tid] = dsum;
    }

    // ---- numW (c = l15 fastest: coalesced 64B segments)
#pragma unroll
    for (int r = 0; r < 4; ++r) {
        const int q = qh2 * 16 + quad * 4 + r;
        const int c = cg * 16 + l15;
        numW[((size_t)f * HW + p0 + q) * CV + c] = acc[r];
    }
}

// ---------------- reduce: sum 9 frame partials, divide ----------------
__global__ __launch_bounds__(256) void cfa_reduce(
    const float* __restrict__ numW, const float* __restrict__ denW,
    float* __restrict__ out)
{
    const int tid = threadIdx.x;
    const int bid = blockIdx.x;            // 0..1023
    const int b = bid >> 8;
    const int p = (bid & 255) * 4 + (tid >> 6);
    const int c = tid & 63;
    float num = 0.f, den = 0.f;
#pragma unroll
    for (int s = 0; s < SAI; ++s) {
        num += numW[(((size_t)(s * NB + b)) * HW + p) * CV + c];
        den += denW[((size_t)(s * NB + b)) * HW + p];
    }
    out[((size_t)b * CV + c) * HW + p] = num / den;
}

// ---------------- fallback (R4-style, proven): used if ws too small ----------
__global__ __launch_bounds__(256, 2) void cfa_fb(
    const float* __restrict__ keys, const float* __restrict__ vals,
    const float* __restrict__ query, const float* __restrict__ disp,
    const int* __restrict__ seq,
    float* __restrict__ numW, float* __restrict__ denW,
    float* __restrict__ out, int nS)
{
    __shared__ alignas(16) unsigned int sV[CV * RSTR];
    __shared__ alignas(16) unsigned int sWb[32 * RSTR];
    __shared__ float sDen[4 * 32];
    __shared__ float sDenTot[32];

    const int tid  = threadIdx.x;
    const int w    = tid >> 6;
    const int lane = tid & 63;
    const int l15  = lane & 15;
    const int quad = lane >> 4;
    const int b    = blockIdx.y;
    const int s0   = blockIdx.z;
    const int p0   = blockIdx.x * 32;
    const bool direct = (nS == SAI);

    bf16x8 qhi[2][2], qlo[2][2];
#pragma unroll
    for (int qt = 0; qt < 2; ++qt)
#pragma unroll
        for (int ks = 0; ks < 2; ++ks)
#pragma unroll
            for (int j = 0; j < 8; ++j) {
                float x = query[(size_t)(b * CK + ks * 32 + quad * 8 + j) * HW + p0 + qt * 16 + l15];
                u16 h = f2bf(x);
                qhi[qt][ks][j] = (short)h;
                qlo[qt][ks][j] = (short)f2bf(x - bf2f(h));
            }

    f32x4 acc[2];
#pragma unroll
    for (int qt = 0; qt < 2; ++qt)
#pragma unroll
        for (int r = 0; r < 4; ++r) acc[qt][r] = 0.f;
    float denacc[2][4] = {{0.f,0.f,0.f,0.f},{0.f,0.f,0.f,0.f}};

    for (int si = 0; si < nS; ++si) {
        const int s = s0 + si;
        const float d0 = (float)seq[(b * SAI + s) * 2 + 0] - 5.f;
        const float d1 = (float)seq[(b * SAI + s) * 2 + 1] - 5.f;
        const float dist = sqrtf(d0 * d0 + d1 * d1);
        const float* Kf = keys + (size_t)(s * NB + b) * CK * HW;
        const float* Vf = vals + (size_t)(s * NB + b) * CV * HW;

        for (int t = 0; t < HW / 128; ++t) {
            const int t128 = t * 128;
            __syncthreads();
#pragma unroll
            for (int it = 0; it < 4; ++it) {
                const int gidx = it * 256 + tid;
                const int c = gidx >> 4;
                const int g = gidx & 15;
                const float* vp = Vf + (size_t)c * HW + t128 + g * 8;
                const float4 f0 = *(const float4*)(vp);
                const float4 f1 = *(const float4*)(vp + 4);
                uint4 pk;
                pk.x = pk2(f0.x, f0.y); pk.y = pk2(f0.z, f0.w);
                pk.z = pk2(f1.x, f1.y); pk.w = pk2(f1.z, f1.w);
                *(uint4*)&sV[c * RSTR + g * 4] = pk;
            }

            f32x4 sc[2][2];
#pragma unroll
            for (int qt = 0; qt < 2; ++qt)
#pragma unroll
                for (int kt = 0; kt < 2; ++kt)
#pragma unroll
                    for (int r = 0; r < 4; ++r) sc[qt][kt][r] = 0.f;

            const int keyBase = t128 + w * 32 + l15;
#pragma unroll
            for (int kt = 0; kt < 2; ++kt)
#pragma unroll
                for (int ks = 0; ks < 2; ++ks) {
                    bf16x8 kh, kl;
#pragma unroll
                    for (int j = 0; j < 8; ++j) {
                        float x = Kf[(size_t)(ks * 32 + quad * 8 + j) * HW + keyBase + kt * 16];
                        u16 h = f2bf(x);
                        kh[j] = (short)h;
                        kl[j] = (short)f2bf(x - bf2f(h));
                    }
#pragma unroll
                    for (int qt = 0; qt < 2; ++qt) {
                        sc[qt][kt] = __builtin_amdgcn_mfma_f32_16x16x32_bf16(qhi[qt][ks], kh, sc[qt][kt], 0, 0, 0);
                        sc[qt][kt] = __builtin_amdgcn_mfma_f32_16x16x32_bf16(qhi[qt][ks], kl, sc[qt][kt], 0, 0, 0);
                        sc[qt][kt] = __builtin_amdgcn_mfma_f32_16x16x32_bf16(qlo[qt][ks], kh, sc[qt][kt], 0, 0, 0);
                    }
                }

#pragma unroll
            for (int kt = 0; kt < 2; ++kt) {
                const int kk = w * 32 + kt * 16 + l15;
                const float dvv = disp[b * HW + t128 + kk];
                const float msk = (fabsf(dist * dvv) > 0.5f) ? 1.f : 0.f;
#pragma unroll
                for (int qt = 0; qt < 2; ++qt)
#pragma unroll
                    for (int r = 0; r < 4; ++r) {
                        const float e = msk * __expf(sc[qt][kt][r]);
                        denacc[qt][r] += e;
                        const int q = qt * 16 + quad * 4 + r;
                        ((u16*)sWb)[q * (2 * RSTR) + kk] = f2bf(e);
                    }
            }
            __syncthreads();

            const int c = w * 16 + l15;
#pragma unroll
            for (int ks2 = 0; ks2 < 4; ++ks2) {
                const int g = ks2 * 4 + quad;
                uint4 vr = *(uint4*)&sV[c * RSTR + g * 4];
                bf16x8 vfrag = __builtin_bit_cast(bf16x8, vr);
#pragma unroll
                for (int qt = 0; qt < 2; ++qt) {
                    const int q = qt * 16 + l15;
                    uint4 wr = *(uint4*)&sWb[q * RSTR + g * 4];
                    bf16x8 wfrag = __builtin_bit_cast(bf16x8, wr);
                    acc[qt] = __builtin_amdgcn_mfma_f32_16x16x32_bf16(wfrag, vfrag, acc[qt], 0, 0, 0);
                }
            }
        }
    }

#pragma unroll
    for (int off = 1; off < 16; off <<= 1)
#pragma unroll
        for (int qt = 0; qt < 2; ++qt)
#pragma unroll
            for (int r = 0; r < 4; ++r)
                denacc[qt][r] += __shfl_xor(denacc[qt][r], off, 64);

    if (l15 == 0)
#pragma unroll
        for (int qt = 0; qt < 2; ++qt)
#pragma unroll
            for (int r = 0; r < 4; ++r)
                sDen[w * 32 + qt * 16 + quad * 4 + r] = denacc[qt][r];
    __syncthreads();

    if (tid < 32) {
        const float d = sDen[tid] + sDen[32 + tid] + sDen[64 + tid] + sDen[96 + tid];
        if (direct) sDenTot[tid] = d;
        else        denW[(size_t)(s0 * NB + b) * HW + p0 + tid] = d;
    }

    if (direct) {
        __syncthreads();
#pragma unroll
        for (int qt = 0; qt < 2; ++qt)
#pragma unroll
            for (int r = 0; r < 4; ++r) {
                const int q = qt * 16 + quad * 4 + r;
                const int c = w * 16 + l15;
                out[((size_t)b * CV + c) * HW + p0 + q] = acc[qt][r] / sDenTot[q];
            }
    } else {
#pragma unroll
        for (int qt = 0; qt < 2; ++qt)
#pragma unroll
            for (int r = 0; r < 4; ++r) {
                const int q = qt * 16 + quad * 4 + r;
                const int c = w * 16 + l15;
                numW[((size_t)(s0 * NB + b) * HW + p0 + q) * CV + c] = acc[qt][r];
            }
    }
}

extern "C" void kernel_launch(void* const* d_in, const int* in_sizes, int n_in,
                              void* d_out, int out_size, void* d_ws, size_t ws_size,
                              hipStream_t stream) {
    const float* keys  = (const float*)d_in[0];
    const float* vals  = (const float*)d_in[1];
    const float* query = (const float*)d_in[2];
    const float* disp  = (const float*)d_in[3];
    const int*   seq   = (const int*)d_in[4];
    float* out = (float*)d_out;

    const size_t numElems = (size_t)SAI * NB * HW * CV;     // 2359296
    const size_t denElems = (size_t)SAI * NB * HW;          // 36864
    const size_t partBytes = (numElems + denElems) * sizeof(float);  // 9584640
    const size_t fragBytes = (size_t)SAI * NB * CK * HW * 2;         // 4718592 each
    const size_t needFull = partBytes + 2 * fragBytes;               // ~18 MiB

    float* numW = (float*)d_ws;
    float* denW = numW + numElems;

    if (ws_size >= needFull) {
        u16* khi = (u16*)((char*)d_ws + partBytes);
        u16* vbf = (u16*)((char*)khi + fragBytes);
        hipLaunchKernelGGL(cfa_prep, dim3(2 * SAI * NB * 8192 / 256), dim3(256), 0, stream,
                           keys, vals, khi, vbf);
        hipLaunchKernelGGL(cfa_main, dim3(36 * (HW / QT)), dim3(512), 0, stream,
                           khi, vbf, query, disp, seq, numW, denW);
        hipLaunchKernelGGL(cfa_reduce, dim3(1024), dim3(256), 0, stream,
                           numW, denW, out);
    } else if (ws_size >= partBytes) {
        hipLaunchKernelGGL(cfa_fb, dim3(HW / 32, NB, SAI), dim3(256), 0, stream,
                           keys, vals, query, disp, seq, numW, denW, (float*)nullptr, 1);
        hipLaunchKernelGGL(cfa_reduce, dim3(1024), dim3(256), 0, stream,
                           numW, denW, out);
    } else {
        hipLaunchKernelGGL(cfa_fb, dim3(HW / 32, NB, 1), dim3(256), 0, stream,
                           keys, vals, query, disp, seq,
                           (float*)nullptr, (float*)nullptr, out, SAI);
    }
}

// Round 15
// 107.230 us; speedup vs baseline: 1.3121x; 1.2383x over previous
//
#include <hip/hip_runtime.h>
#include <math.h>

#define SAI 9
#define NB  4
#define CK  64
#define CV  64
#define HW  1024
#define QT  32    // queries per block
#define RSW 136   // sW row stride in shorts (272 B, b128-aligned rows)
#define RSTR 68   // fallback kernel LDS stride (words)

typedef __attribute__((ext_vector_type(8))) short bf16x8;
typedef __attribute__((ext_vector_type(4))) float f32x4;
typedef unsigned short u16;
typedef unsigned int u32;

__device__ __forceinline__ u16 f2bf(float x) {           // RNE fp32->bf16
    unsigned u = __float_as_uint(x);
    return (u16)((u + 0x7fff + ((u >> 16) & 1)) >> 16);
}
__device__ __forceinline__ float bf2f(u16 s) {
    return __uint_as_float(((unsigned)s) << 16);
}
__device__ __forceinline__ unsigned pk2(float a, float b) {   // RNE pair pack
    return (unsigned)f2bf(a) | ((unsigned)f2bf(b) << 16);
}
// Barrier that waits only LDS (lgkmcnt), leaving global loads in flight.
__device__ __forceinline__ void lds_barrier() {
    __asm__ __volatile__("s_waitcnt lgkmcnt(0)\n\ts_barrier" ::: "memory");
}

// ---------------- prep: fp32 -> bf16 fragments in MFMA order ----------------
// K granule gg = g16*2+ks: elem(lane,j) = K[c=ks*32+quad*8+j][p=g16*16+l15] (hi only)
// V granule gg = kb*4+cg:  elem(lane,j) = V[p=kb*32+quad*8+j][c=cg*16+l15]
// Score error from dropping K-lo is carried by Q hi/lo split in cfa_main.
__global__ __launch_bounds__(256) void cfa_prep(
    const float* __restrict__ keys, const float* __restrict__ vals,
    u16* __restrict__ khi, u16* __restrict__ vbf)
{
    const int gid = blockIdx.x * 256 + threadIdx.x;
    const int isV = gid >= (SAI * NB * 8192);
    const int id  = isV ? gid - SAI * NB * 8192 : gid;
    const int f   = id >> 13;            // frame = s*NB+b
    const int r   = id & 8191;
    const int lane = r & 63;
    const int gg   = r >> 6;             // 0..127
    const int l15 = lane & 15, quad = lane >> 4;
    const size_t fb = (size_t)f * (64 * 1024);

    if (!isV) {
        const int p  = (gg >> 1) * 16 + l15;
        const int c0 = (gg & 1) * 32 + quad * 8;
        const float* src = keys + fb + (size_t)c0 * HW + p;
        float x[8];
#pragma unroll
        for (int j = 0; j < 8; ++j) x[j] = src[(size_t)j * HW];
        uint4 ph;
        u32* php = (u32*)&ph;
#pragma unroll
        for (int h2 = 0; h2 < 4; ++h2)
            php[h2] = pk2(x[h2 * 2], x[h2 * 2 + 1]);
        *(uint4*)&khi[fb + (size_t)gg * 512 + lane * 8] = ph;
    } else {
        const int p = (gg >> 2) * 32 + quad * 8;
        const int c = (gg & 3) * 16 + l15;
        const float* src = vals + fb + (size_t)c * HW + p;
        const float4 a = *(const float4*)src;
        const float4 b = *(const float4*)(src + 4);
        uint4 pv;
        pv.x = pk2(a.x, a.y); pv.y = pk2(a.z, a.w);
        pv.z = pk2(b.x, b.y); pv.w = pk2(b.z, b.w);
        *(uint4*)&vbf[fb + (size_t)gg * 512 + lane * 8] = pv;
    }
}

// ---------------- main: pipelined, lgkm-only barrier, 2-term QK ------------
// Grid = 1152 linear blocks; f = i % 36, qt = i / 36 (XCD frame clustering).
// Wave w owns keys [t*128+w*32,+32). phase1: A=K(hi), B=Q(hi)+Q(lo) ->
//   S = kh.qh + kh.ql (dropped qh.kl term: score err std ~0.006).
// exp -> sW[t&1]. phase2: A=W(all 128 keys), B=V -> acc row=q,col=c.
// K(t+1) prefetched before the lgkm-only barrier (loads stay in flight).
// NOTE (R13/R14): 512-thread fat-tile variants regressed — (512,4) caps
// VGPR at 64 (67 MB spill); (512,2) fixes spills but occupancy drops to
// 18% (1 block/CU). 256-thread / (256,4) is the measured optimum.
__global__ __launch_bounds__(256, 4) void cfa_main(
    const u16* __restrict__ khi, const u16* __restrict__ vbf,
    const float* __restrict__ query, const float* __restrict__ disp,
    const int* __restrict__ seq,
    float* __restrict__ numW, float* __restrict__ denW)
{
    __shared__ alignas(16) u16 sW[2][QT * RSW];   // 2 x 8704 B
    __shared__ float sDen[4 * QT];

    const int tid = threadIdx.x;
    const int w = tid >> 6;
    const int lane = tid & 63;
    const int l15 = lane & 15, quad = lane >> 4;
    const int f  = blockIdx.x % 36;     // frame = s*NB+b
    const int qt = blockIdx.x / 36;     // query tile
    const int s  = f / NB;
    const int b  = f % NB;
    const int p0 = qt * QT;
    const size_t fb = (size_t)f * (64 * 1024);

    const float d0 = (float)seq[(b * SAI + s) * 2 + 0] - 5.f;
    const float d1 = (float)seq[(b * SAI + s) * 2 + 1] - 5.f;
    const float dist = sqrtf(d0 * d0 + d1 * d1);

    // Q B-frags (n=q -> l15, k=channel -> quad*8+j), hi/lo
    bf16x8 qh[2][2], ql[2][2];
#pragma unroll
    for (int q2 = 0; q2 < 2; ++q2)
#pragma unroll
        for (int ks = 0; ks < 2; ++ks)
#pragma unroll
            for (int j = 0; j < 8; ++j) {
                float x = query[(size_t)(b * CK + ks * 32 + quad * 8 + j) * HW + p0 + q2 * 16 + l15];
                u16 h = f2bf(x);
                qh[q2][ks][j] = (short)h;
                ql[q2][ks][j] = (short)f2bf(x - bf2f(h));
            }

    f32x4 acc[2];
#pragma unroll
    for (int q2 = 0; q2 < 2; ++q2)
#pragma unroll
        for (int r = 0; r < 4; ++r) acc[q2][r] = 0.f;
    float den[2] = {0.f, 0.f};

    uint4 kbh[2][2];    // K register buffer [kt][ks]
#define LOADK(tt)                                                              \
    {                                                                          \
        _Pragma("unroll") for (int kt = 0; kt < 2; ++kt)                       \
        _Pragma("unroll") for (int ks = 0; ks < 2; ++ks) {                     \
            const size_t ka = fb +                                             \
                (size_t)((((tt) * 8 + w * 2 + kt) * 2) + ks) * 512 + lane * 8; \
            kbh[kt][ks] = *(const uint4*)&khi[ka];                             \
        }                                                                      \
    }

    LOADK(0);   // prologue: K(0) in flight

    for (int t = 0; t < 8; ++t) {
        u16* const wbuf = sW[t & 1];

        // ---- issue V(t) + disp(t) (consumed post-barrier / post-phase1)
        uint4 vb[4];
#pragma unroll
        for (int k2 = 0; k2 < 4; ++k2)
            vb[k2] = *(const uint4*)&vbf[fb + (size_t)((t * 4 + k2) * 4 + w) * 512 + lane * 8];
        const float4 dv0 = *(const float4*)(disp + b * HW + t * 128 + w * 32 + quad * 4);
        const float4 dv1 = *(const float4*)(disp + b * HW + t * 128 + w * 32 + 16 + quad * 4);

        // ---- phase 1: S for this wave's 32 keys (K already in regs)
        f32x4 sc[2][2];
#pragma unroll
        for (int q2 = 0; q2 < 2; ++q2)
#pragma unroll
            for (int kt = 0; kt < 2; ++kt)
#pragma unroll
                for (int r = 0; r < 4; ++r) sc[q2][kt][r] = 0.f;

#pragma unroll
        for (int kt = 0; kt < 2; ++kt)
#pragma unroll
            for (int ks = 0; ks < 2; ++ks) {
                const bf16x8 kh = __builtin_bit_cast(bf16x8, kbh[kt][ks]);
#pragma unroll
                for (int q2 = 0; q2 < 2; ++q2) {
                    sc[q2][kt] = __builtin_amdgcn_mfma_f32_16x16x32_bf16(kh, qh[q2][ks], sc[q2][kt], 0, 0, 0);
                    sc[q2][kt] = __builtin_amdgcn_mfma_f32_16x16x32_bf16(kh, ql[q2][ks], sc[q2][kt], 0, 0, 0);
                }
            }

        // ---- mask + exp -> sW[t&1] (b64 packed stores), den partials
#pragma unroll
        for (int kt = 0; kt < 2; ++kt) {
            const float4 dv = kt ? dv1 : dv0;
            const float m0 = (fabsf(dist * dv.x) > 0.5f) ? 1.f : 0.f;
            const float m1 = (fabsf(dist * dv.y) > 0.5f) ? 1.f : 0.f;
            const float m2 = (fabsf(dist * dv.z) > 0.5f) ? 1.f : 0.f;
            const float m3 = (fabsf(dist * dv.w) > 0.5f) ? 1.f : 0.f;
#pragma unroll
            for (int q2 = 0; q2 < 2; ++q2) {
                const float e0 = m0 * __expf(sc[q2][kt][0]);
                const float e1 = m1 * __expf(sc[q2][kt][1]);
                const float e2 = m2 * __expf(sc[q2][kt][2]);
                const float e3 = m3 * __expf(sc[q2][kt][3]);
                den[q2] += (e0 + e1) + (e2 + e3);
                uint2 pk;
                pk.x = pk2(e0, e1);
                pk.y = pk2(e2, e3);
                *(uint2*)&wbuf[(q2 * 16 + l15) * RSW + w * 32 + kt * 16 + quad * 4] = pk;
            }
        }

        // ---- prefetch K(t+1): in flight across barrier + phase2
        LOADK((t + 1) & 7);

        lds_barrier();   // waits lgkmcnt only; vmcnt (K/V loads) NOT drained

        // ---- phase 2: acc += W.V (wave w: channels w*16..+15, all 128 keys)
#pragma unroll
        for (int k2 = 0; k2 < 4; ++k2) {
            const bf16x8 vf = __builtin_bit_cast(bf16x8, vb[k2]);
#pragma unroll
            for (int q2 = 0; q2 < 2; ++q2) {
                const bf16x8 wf = __builtin_bit_cast(bf16x8,
                    *(const uint4*)&wbuf[(q2 * 16 + l15) * RSW + k2 * 32 + quad * 8]);
                acc[q2] = __builtin_amdgcn_mfma_f32_16x16x32_bf16(wf, vf, acc[q2], 0, 0, 0);
            }
        }
    }
#undef LOADK

    // ---- den: sum over quads (shfl 16/32), stage per-wave, sum over waves
#pragma unroll
    for (int q2 = 0; q2 < 2; ++q2) {
        den[q2] += __shfl_xor(den[q2], 16, 64);
        den[q2] += __shfl_xor(den[q2], 32, 64);
    }
    if (quad == 0) {
#pragma unroll
        for (int q2 = 0; q2 < 2; ++q2)
            sDen[w * QT + q2 * 16 + l15] = den[q2];
    }
    __syncthreads();
    if (tid < QT)
        denW[(size_t)f * HW + p0 + tid] =
            sDen[tid] + sDen[QT + tid] + sDen[2 * QT + tid] + sDen[3 * QT + tid];

    // ---- numW (c = l15 fastest: coalesced 64B segments)
#pragma unroll
    for (int q2 = 0; q2 < 2; ++q2)
#pragma unroll
        for (int r = 0; r < 4; ++r) {
            const int q = q2 * 16 + quad * 4 + r;
            const int c = w * 16 + l15;
            numW[((size_t)f * HW + p0 + q) * CV + c] = acc[q2][r];
        }
}

// ---------------- reduce: sum 9 frame partials, divide ----------------
__global__ __launch_bounds__(256) void cfa_reduce(
    const float* __restrict__ numW, const float* __restrict__ denW,
    float* __restrict__ out)
{
    const int tid = threadIdx.x;
    const int bid = blockIdx.x;            // 0..1023
    const int b = bid >> 8;
    const int p = (bid & 255) * 4 + (tid >> 6);
    const int c = tid & 63;
    float num = 0.f, den = 0.f;
#pragma unroll
    for (int s = 0; s < SAI; ++s) {
        num += numW[(((size_t)(s * NB + b)) * HW + p) * CV + c];
        den += denW[((size_t)(s * NB + b)) * HW + p];
    }
    out[((size_t)b * CV + c) * HW + p] = num / den;
}

// ---------------- fallback (R4-style, proven): used if ws too small ----------
__global__ __launch_bounds__(256, 2) void cfa_fb(
    const float* __restrict__ keys, const float* __restrict__ vals,
    const float* __restrict__ query, const float* __restrict__ disp,
    const int* __restrict__ seq,
    float* __restrict__ numW, float* __restrict__ denW,
    float* __restrict__ out, int nS)
{
    __shared__ alignas(16) unsigned int sV[CV * RSTR];
    __shared__ alignas(16) unsigned int sWb[32 * RSTR];
    __shared__ float sDen[4 * 32];
    __shared__ float sDenTot[32];

    const int tid  = threadIdx.x;
    const int w    = tid >> 6;
    const int lane = tid & 63;
    const int l15  = lane & 15;
    const int quad = lane >> 4;
    const int b    = blockIdx.y;
    const int s0   = blockIdx.z;
    const int p0   = blockIdx.x * 32;
    const bool direct = (nS == SAI);

    bf16x8 qhi[2][2], qlo[2][2];
#pragma unroll
    for (int qt = 0; qt < 2; ++qt)
#pragma unroll
        for (int ks = 0; ks < 2; ++ks)
#pragma unroll
            for (int j = 0; j < 8; ++j) {
                float x = query[(size_t)(b * CK + ks * 32 + quad * 8 + j) * HW + p0 + qt * 16 + l15];
                u16 h = f2bf(x);
                qhi[qt][ks][j] = (short)h;
                qlo[qt][ks][j] = (short)f2bf(x - bf2f(h));
            }

    f32x4 acc[2];
#pragma unroll
    for (int qt = 0; qt < 2; ++qt)
#pragma unroll
        for (int r = 0; r < 4; ++r) acc[qt][r] = 0.f;
    float denacc[2][4] = {{0.f,0.f,0.f,0.f},{0.f,0.f,0.f,0.f}};

    for (int si = 0; si < nS; ++si) {
        const int s = s0 + si;
        const float d0 = (float)seq[(b * SAI + s) * 2 + 0] - 5.f;
        const float d1 = (float)seq[(b * SAI + s) * 2 + 1] - 5.f;
        const float dist = sqrtf(d0 * d0 + d1 * d1);
        const float* Kf = keys + (size_t)(s * NB + b) * CK * HW;
        const float* Vf = vals + (size_t)(s * NB + b) * CV * HW;

        for (int t = 0; t < HW / 128; ++t) {
            const int t128 = t * 128;
            __syncthreads();
#pragma unroll
            for (int it = 0; it < 4; ++it) {
                const int gidx = it * 256 + tid;
                const int c = gidx >> 4;
                const int g = gidx & 15;
                const float* vp = Vf + (size_t)c * HW + t128 + g * 8;
                const float4 f0 = *(const float4*)(vp);
                const float4 f1 = *(const float4*)(vp + 4);
                uint4 pk;
                pk.x = pk2(f0.x, f0.y); pk.y = pk2(f0.z, f0.w);
                pk.z = pk2(f1.x, f1.y); pk.w = pk2(f1.z, f1.w);
                *(uint4*)&sV[c * RSTR + g * 4] = pk;
            }

            f32x4 sc[2][2];
#pragma unroll
            for (int qt = 0; qt < 2; ++qt)
#pragma unroll
                for (int kt = 0; kt < 2; ++kt)
#pragma unroll
                    for (int r = 0; r < 4; ++r) sc[qt][kt][r] = 0.f;

            const int keyBase = t128 + w * 32 + l15;
#pragma unroll
            for (int kt = 0; kt < 2; ++kt)
#pragma unroll
                for (int ks = 0; ks < 2; ++ks) {
                    bf16x8 kh, kl;
#pragma unroll
                    for (int j = 0; j < 8; ++j) {
                        float x = Kf[(size_t)(ks * 32 + quad * 8 + j) * HW + keyBase + kt * 16];
                        u16 h = f2bf(x);
                        kh[j] = (short)h;
                        kl[j] = (short)f2bf(x - bf2f(h));
                    }
#pragma unroll
                    for (int qt = 0; qt < 2; ++qt) {
                        sc[qt][kt] = __builtin_amdgcn_mfma_f32_16x16x32_bf16(qhi[qt][ks], kh, sc[qt][kt], 0, 0, 0);
                        sc[qt][kt] = __builtin_amdgcn_mfma_f32_16x16x32_bf16(qhi[qt][ks], kl, sc[qt][kt], 0, 0, 0);
                        sc[qt][kt] = __builtin_amdgcn_mfma_f32_16x16x32_bf16(qlo[qt][ks], kh, sc[qt][kt], 0, 0, 0);
                    }
                }

#pragma unroll
            for (int kt = 0; kt < 2; ++kt) {
                const int kk = w * 32 + kt * 16 + l15;
                const float dvv = disp[b * HW + t128 + kk];
                const float msk = (fabsf(dist * dvv) > 0.5f) ? 1.f : 0.f;
#pragma unroll
                for (int qt = 0; qt < 2; ++qt)
#pragma unroll
                    for (int r = 0; r < 4; ++r) {
                        const float e = msk * __expf(sc[qt][kt][r]);
                        denacc[qt][r] += e;
                        const int q = qt * 16 + quad * 4 + r;
                        ((u16*)sWb)[q * (2 * RSTR) + kk] = f2bf(e);
                    }
            }
            __syncthreads();

            const int c = w * 16 + l15;
#pragma unroll
            for (int ks2 = 0; ks2 < 4; ++ks2) {
                const int g = ks2 * 4 + quad;
                uint4 vr = *(uint4*)&sV[c * RSTR + g * 4];
                bf16x8 vfrag = __builtin_bit_cast(bf16x8, vr);
#pragma unroll
                for (int qt = 0; qt < 2; ++qt) {
                    const int q = qt * 16 + l15;
                    uint4 wr = *(uint4*)&sWb[q * RSTR + g * 4];
                    bf16x8 wfrag = __builtin_bit_cast(bf16x8, wr);
                    acc[qt] = __builtin_amdgcn_mfma_f32_16x16x32_bf16(wfrag, vfrag, acc[qt], 0, 0, 0);
                }
            }
        }
    }

#pragma unroll
    for (int off = 1; off < 16; off <<= 1)
#pragma unroll
        for (int qt = 0; qt < 2; ++qt)
#pragma unroll
            for (int r = 0; r < 4; ++r)
                denacc[qt][r] += __shfl_xor(denacc[qt][r], off, 64);

    if (l15 == 0)
#pragma unroll
        for (int qt = 0; qt < 2; ++qt)
#pragma unroll
            for (int r = 0; r < 4; ++r)
                sDen[w * 32 + qt * 16 + quad * 4 + r] = denacc[qt][r];
    __syncthreads();

    if (tid < 32) {
        const float d = sDen[tid] + sDen[32 + tid] + sDen[64 + tid] + sDen[96 + tid];
        if (direct) sDenTot[tid] = d;
        else        denW[(size_t)(s0 * NB + b) * HW + p0 + tid] = d;
    }

    if (direct) {
        __syncthreads();
#pragma unroll
        for (int qt = 0; qt < 2; ++qt)
#pragma unroll
            for (int r = 0; r < 4; ++r) {
                const int q = qt * 16 + quad * 4 + r;
                const int c = w * 16 + l15;
                out[((size_t)b * CV + c) * HW + p0 + q] = acc[qt][r] / sDenTot[q];
            }
    } else {
#pragma unroll
        for (int qt = 0; qt < 2; ++qt)
#pragma unroll
            for (int r = 0; r < 4; ++r) {
                const int q = qt * 16 + quad * 4 + r;
                const int c = w * 16 + l15;
                numW[((size_t)(s0 * NB + b) * HW + p0 + q) * CV + c] = acc[qt][r];
            }
    }
}

extern "C" void kernel_launch(void* const* d_in, const int* in_sizes, int n_in,
                              void* d_out, int out_size, void* d_ws, size_t ws_size,
                              hipStream_t stream) {
    const float* keys  = (const float*)d_in[0];
    const float* vals  = (const float*)d_in[1];
    const float* query = (const float*)d_in[2];
    const float* disp  = (const float*)d_in[3];
    const int*   seq   = (const int*)d_in[4];
    float* out = (float*)d_out;

    const size_t numElems = (size_t)SAI * NB * HW * CV;     // 2359296
    const size_t denElems = (size_t)SAI * NB * HW;          // 36864
    const size_t partBytes = (numElems + denElems) * sizeof(float);  // 9584640
    const size_t fragBytes = (size_t)SAI * NB * CK * HW * 2;         // 4718592 each
    const size_t needFull = partBytes + 2 * fragBytes;               // ~18 MiB

    float* numW = (float*)d_ws;
    float* denW = numW + numElems;

    if (ws_size >= needFull) {
        u16* khi = (u16*)((char*)d_ws + partBytes);
        u16* vbf = (u16*)((char*)khi + fragBytes);
        hipLaunchKernelGGL(cfa_prep, dim3(2 * SAI * NB * 8192 / 256), dim3(256), 0, stream,
                           keys, vals, khi, vbf);
        hipLaunchKernelGGL(cfa_main, dim3(36 * (HW / QT)), dim3(256), 0, stream,
                           khi, vbf, query, disp, seq, numW, denW);
        hipLaunchKernelGGL(cfa_reduce, dim3(1024), dim3(256), 0, stream,
                           numW, denW, out);
    } else if (ws_size >= partBytes) {
        hipLaunchKernelGGL(cfa_fb, dim3(HW / 32, NB, SAI), dim3(256), 0, stream,
                           keys, vals, query, disp, seq, numW, denW, (float*)nullptr, 1);
        hipLaunchKernelGGL(cfa_reduce, dim3(1024), dim3(256), 0, stream,
                           numW, denW, out);
    } else {
        hipLaunchKernelGGL(cfa_fb, dim3(HW / 32, NB, 1), dim3(256), 0, stream,
                           keys, vals, query, disp, seq,
                           (float*)nullptr, (float*)nullptr, out, SAI);
    }
}